// Round 1
// baseline (2906.141 us; speedup 1.0000x reference)
//
#include <hip/hip_runtime.h>
#include <hip/hip_bf16.h>
#include <stdint.h>

// Problem constants
#define NA_   1024
#define NT_   1024
#define DD_   128      // A_DIM == E_DIM
#define LL_   128      // L_LABELS
#define KK_   16384    // LL_*DD_

typedef short bf16x8 __attribute__((ext_vector_type(8)));
typedef float f32x4  __attribute__((ext_vector_type(4)));

#define GLD16(g, l) __builtin_amdgcn_global_load_lds( \
    (const __attribute__((address_space(1))) void*)(uintptr_t)(g), \
    (__attribute__((address_space(3))) void*)(uintptr_t)(l), 16, 0, 0)

// ---------------- prep: transpose inputs [1024][1024] -> inputsT ----------------
__global__ __launch_bounds__(256) void transpose_int_kernel(const int* __restrict__ in,
                                                            int* __restrict__ out) {
    __shared__ int tile[32][33];
    int b = blockIdx.x;              // 1024 tiles (32x32 grid of 32x32 tiles)
    int tr = b >> 5, tc = b & 31;
    int r0 = tr * 32, c0 = tc * 32;
    int tx = threadIdx.x & 31, ty = threadIdx.x >> 5;   // ty 0..7
#pragma unroll
    for (int p = 0; p < 4; ++p)
        tile[ty + p * 8][tx] = in[(size_t)(r0 + ty + p * 8) * 1024 + c0 + tx];
    __syncthreads();
#pragma unroll
    for (int p = 0; p < 4; ++p) {
        int cc = ty + p * 8;
        out[(size_t)(c0 + cc) * 1024 + r0 + tx] = tile[tx][cc];
    }
}

// ------------- prep: transpose+cast weights f32 [16384][128] -> bf16 [128][16384] -------------
__global__ __launch_bounds__(256) void transpose_w_kernel(const float* __restrict__ W0,
                                                          const float* __restrict__ W1,
                                                          uint16_t* __restrict__ O0,
                                                          uint16_t* __restrict__ O1) {
    __shared__ float tile[32][33];
    int b = blockIdx.x;              // 4096 tiles total (2048 per weight)
    const float* W = W0;
    uint16_t* O = O0;
    if (b >= 2048) { b -= 2048; W = W1; O = O1; }
    int tr = b >> 2;                 // 0..511 (16384/32)
    int tc = b & 3;                  // 0..3   (128/32)
    int r0 = tr * 32, c0 = tc * 32;
    int tx = threadIdx.x & 31, ty = threadIdx.x >> 5;
#pragma unroll
    for (int p = 0; p < 4; ++p)
        tile[ty + p * 8][tx] = W[(size_t)(r0 + ty + p * 8) * 128 + c0 + tx];
    __syncthreads();
#pragma unroll
    for (int p = 0; p < 4; ++p) {
        int cc = ty + p * 8;
        __hip_bfloat16 h = __float2bfloat16(tile[tx][cc]);
        O[(size_t)(c0 + cc) * 16384 + r0 + tx] = *(uint16_t*)&h;
    }
}

// ---------------- prep: init states ----------------
__global__ __launch_bounds__(256) void copy_states_kernel(const float* __restrict__ fa,
                                                          const float* __restrict__ ft,
                                                          float* __restrict__ a_st,
                                                          float* __restrict__ t_st) {
    int i = blockIdx.x * 256 + threadIdx.x;   // grid 1024 -> 262144 threads
    if (i < 131072) a_st[i] = fa[i];
    else            t_st[i - 131072] = ft[i - 131072];
}

// ---------------- bucket: U[j, l*128+e] = sum_{t: lab[j][t]==l} src[t][e]  (2 j per block) ----------------
__global__ __launch_bounds__(512) void bucket_kernel(const int* __restrict__ idxmat,   // [1024][1024]
                                                     const float* __restrict__ src,    // [1024][128]
                                                     uint16_t* __restrict__ U) {       // [1024][16384] bf16
    __shared__ float u[2 * 16384];   // 128 KiB
    __shared__ int lab[2 * 1024];    // 8 KiB
    const int tid = threadIdx.x;
    const int j0 = blockIdx.x * 2;

    for (int i = tid; i < 2 * 16384; i += 512) u[i] = 0.f;
    for (int i = tid; i < 2 * 1024; i += 512) {
        int jj = i >> 10, t = i & 1023;
        lab[i] = idxmat[(size_t)(j0 + jj) * 1024 + t];
    }
    __syncthreads();

    const int e = tid & 127;
    const int g = tid >> 7;          // 0..3, wave-pair uniform
#pragma unroll 4
    for (int i = 0; i < 256; ++i) {
        int t = i * 4 + g;
        float v = src[(size_t)t * 128 + e];
        int l0 = lab[t];
        int l1 = lab[1024 + t];
        atomicAdd(&u[l0 * 128 + e], v);
        atomicAdd(&u[16384 + l1 * 128 + e], v);
    }
    __syncthreads();

    for (int i = tid; i < 2 * 16384; i += 512) {
        int jj = i >> 14;
        int rest = i & 16383;
        __hip_bfloat16 h = __float2bfloat16(u[i]);
        U[(size_t)(j0 + jj) * 16384 + rest] = *(uint16_t*)&h;
    }
}

// ---------------- GEMM: out[1024][128] += A[1024][16384] x Bt[128][16384]^T (split-K, atomic) ----------------
// grid (8 m-tiles, 32 k-chunks), 256 threads = 4 waves (2x2), 64x64 per wave, 16x16x32 bf16 MFMA.
__global__ __launch_bounds__(256) void gemm_kernel(const uint16_t* __restrict__ A,
                                                   const uint16_t* __restrict__ Bt,
                                                   float* __restrict__ outacc) {
    __shared__ uint16_t Atile[128 * 64];   // 16 KiB, rows of 64 bf16 (128B), XOR-swizzled 16B slots
    __shared__ uint16_t Btile[128 * 64];   // 16 KiB, rows = n (0..127)

    const int tid = threadIdx.x;
    const int lane = tid & 63;
    const int wid = tid >> 6;
    const int wr = wid >> 1, wc = wid & 1;
    const int mbase = blockIdx.x * 128;            // 0..7 m-tiles
    const size_t kchunk = (size_t)blockIdx.y * 512; // 0..31 k-chunks

    f32x4 acc[4][4] = {};

    const int rlane = lane >> 3;   // 0..7
    const int slane = lane & 7;    // 16B slot within 128B row

    for (int it = 0; it < 8; ++it) {
        const size_t kb2 = (kchunk + (size_t)it * 64) * 2;   // byte offset along a 32768B row
#pragma unroll
        for (int c = 0; c < 4; ++c) {
            int r = c * 32 + wid * 8 + rlane;
            int col16 = slane ^ (r & 7);                     // pre-swizzled source (involution)
            const char* gA = (const char*)A + (size_t)(mbase + r) * 32768 + kb2 + col16 * 16;
            char* lA = (char*)Atile + c * 4096 + wid * 1024; // wave-uniform linear dest
            GLD16(gA, lA);
            const char* gB = (const char*)Bt + (size_t)r * 32768 + kb2 + col16 * 16;
            char* lB = (char*)Btile + c * 4096 + wid * 1024;
            GLD16(gB, lB);
        }
        __syncthreads();   // drains vmcnt for global_load_lds

#pragma unroll
        for (int kk = 0; kk < 2; ++kk) {
            bf16x8 af[4], bfr[4];
            const int q = lane >> 4;      // 0..3
            const int rl = lane & 15;
#pragma unroll
            for (int m = 0; m < 4; ++m) {
                int row = wr * 64 + m * 16 + rl;
                int ls = kk * 4 + q;
                int sw = ls ^ (row & 7);
                af[m] = *(const bf16x8*)((const char*)Atile + row * 128 + sw * 16);
            }
#pragma unroll
            for (int n = 0; n < 4; ++n) {
                int row = wc * 64 + n * 16 + rl;
                int ls = kk * 4 + q;
                int sw = ls ^ (row & 7);
                bfr[n] = *(const bf16x8*)((const char*)Btile + row * 128 + sw * 16);
            }
#pragma unroll
            for (int m = 0; m < 4; ++m)
#pragma unroll
                for (int n = 0; n < 4; ++n)
                    acc[m][n] = __builtin_amdgcn_mfma_f32_16x16x32_bf16(af[m], bfr[n], acc[m][n], 0, 0, 0);
        }
        __syncthreads();
    }

    const int rq = lane >> 4;   // C/D: col=lane&15, row=(lane>>4)*4+reg  [m89-verified]
    const int cn = lane & 15;
#pragma unroll
    for (int m = 0; m < 4; ++m)
#pragma unroll
        for (int n = 0; n < 4; ++n)
#pragma unroll
            for (int r = 0; r < 4; ++r) {
                int row = mbase + wr * 64 + m * 16 + rq * 4 + r;
                int col = wc * 64 + n * 16 + cn;
                atomicAdd(&outacc[(size_t)row * 128 + col], acc[m][n][r]);
            }
}

// ---------------- epilogue: build [2048][256] output ----------------
__global__ __launch_bounds__(256) void epilogue_kernel(const float* __restrict__ a_st,
                                                       const float* __restrict__ t_st,
                                                       float* __restrict__ out) {
    int r = blockIdx.x;        // 0..2047
    int c = threadIdx.x;       // 0..255
    float v = 0.f;
    if (c < 128) v = (r < 1024) ? a_st[(size_t)r * 128 + c] : t_st[(size_t)(r - 1024) * 128 + c];
    out[(size_t)r * 256 + c] = v;
}

extern "C" void kernel_launch(void* const* d_in, const int* in_sizes, int n_in,
                              void* d_out, int out_size, void* d_ws, size_t ws_size,
                              hipStream_t stream) {
    const int*   inputs  = (const int*)d_in[0];
    const float* first_a = (const float*)d_in[1];
    const float* first_t = (const float*)d_in[2];
    const float* Awij    = (const float*)d_in[3];
    const float* Awij2   = (const float*)d_in[4];
    float* out = (float*)d_out;

    // workspace layout (45 MiB total)
    char* w = (char*)d_ws;
    int*      inputsT = (int*)(w);                              // 4 MiB
    uint16_t* BtA     = (uint16_t*)(w + (4u << 20));            // 4 MiB  Bt for phase A: [a][l*128+e] = Awij2[l][e][a]
    uint16_t* BtT     = (uint16_t*)(w + (8u << 20));            // 4 MiB  Bt for phase T: [e][l*128+a] = Awij[l][a][e]
    uint16_t* U       = (uint16_t*)(w + (12u << 20));           // 32 MiB bucketed sums (bf16)
    float*    a_st    = (float*)(w + (44u << 20));              // 512 KiB
    float*    t_st    = (float*)(w + (44u << 20) + (1u << 19)); // 512 KiB
    if (ws_size < (45u << 20)) return;

    transpose_int_kernel<<<1024, 256, 0, stream>>>(inputs, inputsT);
    transpose_w_kernel<<<4096, 256, 0, stream>>>(Awij2, Awij, BtA, BtT);
    copy_states_kernel<<<1024, 256, 0, stream>>>(first_a, first_t, a_st, t_st);

    for (int s = 0; s < 2; ++s) {
        // Phase A: a += bucket(t) x Awij2
        bucket_kernel<<<512, 512, 0, stream>>>(inputs, t_st, U);
        gemm_kernel<<<dim3(8, 32), 256, 0, stream>>>(U, BtA, a_st);
        // Phase T: t += bucket(new_a, by column) x Awij
        bucket_kernel<<<512, 512, 0, stream>>>(inputsT, a_st, U);
        gemm_kernel<<<dim3(8, 32), 256, 0, stream>>>(U, BtT, t_st);
    }

    epilogue_kernel<<<2048, 256, 0, stream>>>(a_st, t_st, out);
}

// Round 2
// 379.908 us; speedup vs baseline: 7.6496x; 7.6496x over previous
//
#include <hip/hip_runtime.h>
#include <hip/hip_bf16.h>
#include <stdint.h>

// Problem constants: NA=NT=1024, A_DIM=E_DIM=128, L=128, K = L*128 = 16384

typedef short bf16x8 __attribute__((ext_vector_type(8)));
typedef float f32x4  __attribute__((ext_vector_type(4)));

#define GLD16(g, l) __builtin_amdgcn_global_load_lds( \
    (const __attribute__((address_space(1))) void*)(uintptr_t)(g), \
    (__attribute__((address_space(3))) void*)(uintptr_t)(l), 16, 0, 0)

// ---------------- prep: transpose inputs [1024][1024] -> inputsT ----------------
__global__ __launch_bounds__(256) void transpose_int_kernel(const int* __restrict__ in,
                                                            int* __restrict__ out) {
    __shared__ int tile[32][33];
    int b = blockIdx.x;              // 1024 tiles
    int tr = b >> 5, tc = b & 31;
    int r0 = tr * 32, c0 = tc * 32;
    int tx = threadIdx.x & 31, ty = threadIdx.x >> 5;
#pragma unroll
    for (int p = 0; p < 4; ++p)
        tile[ty + p * 8][tx] = in[(size_t)(r0 + ty + p * 8) * 1024 + c0 + tx];
    __syncthreads();
#pragma unroll
    for (int p = 0; p < 4; ++p) {
        int cc = ty + p * 8;
        out[(size_t)(c0 + cc) * 1024 + r0 + tx] = tile[tx][cc];
    }
}

// ------------- prep: transpose+cast weights f32 [16384][128] -> bf16 [128][16384] -------------
__global__ __launch_bounds__(256) void transpose_w_kernel(const float* __restrict__ W0,
                                                          const float* __restrict__ W1,
                                                          uint16_t* __restrict__ O0,
                                                          uint16_t* __restrict__ O1) {
    __shared__ float tile[32][33];
    int b = blockIdx.x;              // 4096 tiles (2048 per weight)
    const float* W = W0;
    uint16_t* O = O0;
    if (b >= 2048) { b -= 2048; W = W1; O = O1; }
    int tr = b >> 2, tc = b & 3;
    int r0 = tr * 32, c0 = tc * 32;
    int tx = threadIdx.x & 31, ty = threadIdx.x >> 5;
#pragma unroll
    for (int p = 0; p < 4; ++p)
        tile[ty + p * 8][tx] = W[(size_t)(r0 + ty + p * 8) * 128 + c0 + tx];
    __syncthreads();
#pragma unroll
    for (int p = 0; p < 4; ++p) {
        int cc = ty + p * 8;
        __hip_bfloat16 h = __float2bfloat16(tile[tx][cc]);
        O[(size_t)(c0 + cc) * 16384 + r0 + tx] = *(uint16_t*)&h;
    }
}

// ---------------- prep: CSR build (deterministic counting sort per row) ----------------
__global__ __launch_bounds__(128) void csr_build_kernel(const int* __restrict__ inA,
                                                        const int* __restrict__ inT,
                                                        uint16_t* __restrict__ idxA,
                                                        uint16_t* __restrict__ idxT,
                                                        int* __restrict__ offA,
                                                        int* __restrict__ offT) {
    __shared__ int lab[1024];
    __shared__ int hist[128];
    __shared__ int off[128];
    int b = blockIdx.x;
    const int* in = inA; uint16_t* idx = idxA; int* offo = offA; int row = b;
    if (b >= 1024) { in = inT; idx = idxT; offo = offT; row = b - 1024; }
    const int tid = threadIdx.x;
    hist[tid] = 0;
    for (int i = tid; i < 1024; i += 128) lab[i] = in[(size_t)row * 1024 + i];
    __syncthreads();
    for (int i = tid; i < 1024; i += 128) atomicAdd(&hist[lab[i]], 1);
    __syncthreads();
    if (tid == 0) { int s = 0; for (int l = 0; l < 128; ++l) { off[l] = s; s += hist[l]; } }
    __syncthreads();
    int p = off[tid];
    offo[(size_t)row * 128 + tid] = p;
    for (int t = 0; t < 1024; ++t)
        if (lab[t] == tid) idx[(size_t)row * 1024 + (p++)] = (uint16_t)t;
}

// ---------------- prep: init output (state lives in d_out, stride 256) ----------------
__global__ __launch_bounds__(256) void init_out_kernel(const float* __restrict__ fa,
                                                       const float* __restrict__ ft,
                                                       float* __restrict__ out) {
    int i = blockIdx.x * 256 + threadIdx.x;   // grid 2048 -> 524288
    int r = i >> 8, c = i & 255;
    float v = 0.f;
    if (c < 128) v = (r < 1024) ? fa[(size_t)r * 128 + c] : ft[(size_t)(r - 1024) * 128 + c];
    out[i] = v;
}

// ---------------- bucket via CSR: U[j, l*128+e] = sum_{t in list(j,l)} src[t][e] ----------------
// 1 block per j, 8 waves, 16 labels per wave, lane covers 2 e-channels. No atomics, no LDS.
__global__ __launch_bounds__(512) void bucket_csr_kernel(const uint16_t* __restrict__ idx,
                                                         const int* __restrict__ off,
                                                         const float* __restrict__ src,   // stride 256
                                                         uint32_t* __restrict__ U32) {    // [1024][8192]
    const int j = blockIdx.x;
    const int wv = threadIdx.x >> 6, lane = threadIdx.x & 63;
    const uint16_t* ridx = idx + (size_t)j * 1024;
    const int* roff = off + (size_t)j * 128;
#pragma unroll 1
    for (int li = 0; li < 16; ++li) {
        int l = wv * 16 + li;
        int s = roff[l];
        int e = (l < 127) ? roff[l + 1] : 1024;
        float a0 = 0.f, a1 = 0.f;
        int p = s;
        for (; p + 1 < e; p += 2) {
            int t0 = ridx[p], t1 = ridx[p + 1];
            float2 v0 = *(const float2*)(src + (size_t)t0 * 256 + lane * 2);
            float2 v1 = *(const float2*)(src + (size_t)t1 * 256 + lane * 2);
            a0 += v0.x + v1.x;
            a1 += v0.y + v1.y;
        }
        if (p < e) {
            int t0 = ridx[p];
            float2 v0 = *(const float2*)(src + (size_t)t0 * 256 + lane * 2);
            a0 += v0.x; a1 += v0.y;
        }
        __hip_bfloat16 h0 = __float2bfloat16(a0), h1 = __float2bfloat16(a1);
        uint32_t pk = ((uint32_t)(*(uint16_t*)&h1) << 16) | (uint32_t)(*(uint16_t*)&h0);
        U32[(size_t)j * 8192 + l * 64 + lane] = pk;
    }
}

// ---------------- GEMM: state[1024][*256] += A[1024][16384] x Bt[128][16384]^T ----------------
// grid (8 m-tiles, 32 k-chunks), 256 threads = 4 waves (2x2), 64x64 per wave, 16x16x32 bf16 MFMA.
// Output accumulate via native f32 atomic (unsafeAtomicAdd), state stride 256.
__global__ __launch_bounds__(256) void gemm_kernel(const uint16_t* __restrict__ A,
                                                   const uint16_t* __restrict__ Bt,
                                                   float* __restrict__ outacc) {
    __shared__ uint16_t Atile[128 * 64];   // 16 KiB, XOR-swizzled 16B slots
    __shared__ uint16_t Btile[128 * 64];

    const int tid = threadIdx.x;
    const int lane = tid & 63;
    const int wid = tid >> 6;
    const int wr = wid >> 1, wc = wid & 1;
    const int mbase = blockIdx.x * 128;
    const size_t kchunk = (size_t)blockIdx.y * 512;

    f32x4 acc[4][4] = {};

    const int rlane = lane >> 3;
    const int slane = lane & 7;

    for (int it = 0; it < 8; ++it) {
        const size_t kb2 = (kchunk + (size_t)it * 64) * 2;
#pragma unroll
        for (int c = 0; c < 4; ++c) {
            int r = c * 32 + wid * 8 + rlane;
            int col16 = slane ^ (r & 7);                     // pre-swizzled source (involution)
            const char* gA = (const char*)A + (size_t)(mbase + r) * 32768 + kb2 + col16 * 16;
            char* lA = (char*)Atile + c * 4096 + wid * 1024; // wave-uniform linear dest
            GLD16(gA, lA);
            const char* gB = (const char*)Bt + (size_t)r * 32768 + kb2 + col16 * 16;
            char* lB = (char*)Btile + c * 4096 + wid * 1024;
            GLD16(gB, lB);
        }
        __syncthreads();

#pragma unroll
        for (int kk = 0; kk < 2; ++kk) {
            bf16x8 af[4], bfr[4];
            const int q = lane >> 4;
            const int rl = lane & 15;
#pragma unroll
            for (int m = 0; m < 4; ++m) {
                int row = wr * 64 + m * 16 + rl;
                int sw = (kk * 4 + q) ^ (row & 7);
                af[m] = *(const bf16x8*)((const char*)Atile + row * 128 + sw * 16);
            }
#pragma unroll
            for (int n = 0; n < 4; ++n) {
                int row = wc * 64 + n * 16 + rl;
                int sw = (kk * 4 + q) ^ (row & 7);
                bfr[n] = *(const bf16x8*)((const char*)Btile + row * 128 + sw * 16);
            }
#pragma unroll
            for (int m = 0; m < 4; ++m)
#pragma unroll
                for (int n = 0; n < 4; ++n)
                    acc[m][n] = __builtin_amdgcn_mfma_f32_16x16x32_bf16(af[m], bfr[n], acc[m][n], 0, 0, 0);
        }
        __syncthreads();
    }

    const int rq = lane >> 4;   // C/D: col=lane&15, row=(lane>>4)*4+reg
    const int cn = lane & 15;
#pragma unroll
    for (int m = 0; m < 4; ++m)
#pragma unroll
        for (int n = 0; n < 4; ++n)
#pragma unroll
            for (int r = 0; r < 4; ++r) {
                int row = mbase + wr * 64 + m * 16 + rq * 4 + r;
                int col = wc * 64 + n * 16 + cn;
                unsafeAtomicAdd(&outacc[(size_t)row * 256 + col], acc[m][n][r]);
            }
}

extern "C" void kernel_launch(void* const* d_in, const int* in_sizes, int n_in,
                              void* d_out, int out_size, void* d_ws, size_t ws_size,
                              hipStream_t stream) {
    const int*   inputs  = (const int*)d_in[0];
    const float* first_a = (const float*)d_in[1];
    const float* first_t = (const float*)d_in[2];
    const float* Awij    = (const float*)d_in[3];
    const float* Awij2   = (const float*)d_in[4];
    float* out = (float*)d_out;

    // workspace layout (45 MiB total, same guard as the passing round-0 kernel)
    char* w = (char*)d_ws;
    uint16_t* U       = (uint16_t*)(w);                 // 32 MiB  [1024][16384] bf16
    int*      inputsT = (int*)(w);                      // 4 MiB, prep-only, aliases U
    uint16_t* BtA     = (uint16_t*)(w + (32u << 20));   // 4 MiB  [a][l*128+e] = Awij2[l][e][a]
    uint16_t* BtT     = (uint16_t*)(w + (36u << 20));   // 4 MiB  [e][l*128+a] = Awij[l][a][e]
    uint16_t* idxA    = (uint16_t*)(w + (40u << 20));   // 2 MiB
    uint16_t* idxT    = (uint16_t*)(w + (42u << 20));   // 2 MiB
    int*      offA    = (int*)(w + (44u << 20));        // 512 KiB
    int*      offT    = (int*)(w + (44u << 20) + (1u << 19)); // 512 KiB
    if (ws_size < (45u << 20)) return;

    float* stateA = out;                 // [1024][256], cols 0..127 live
    float* stateT = out + 1024 * 256;    // [1024][256], cols 0..127 live

    transpose_int_kernel<<<1024, 256, 0, stream>>>(inputs, inputsT);
    transpose_w_kernel<<<4096, 256, 0, stream>>>(Awij2, Awij, BtA, BtT);
    csr_build_kernel<<<2048, 128, 0, stream>>>(inputs, inputsT, idxA, idxT, offA, offT);
    init_out_kernel<<<2048, 256, 0, stream>>>(first_a, first_t, out);

    for (int s = 0; s < 2; ++s) {
        // Phase A: a += bucket_t(update_t) x Awij2
        bucket_csr_kernel<<<1024, 512, 0, stream>>>(idxA, offA, stateT, (uint32_t*)U);
        gemm_kernel<<<dim3(8, 32), 256, 0, stream>>>(U, BtA, stateA);
        // Phase T: t += bucket_j(new_a) x Awij
        bucket_csr_kernel<<<1024, 512, 0, stream>>>(idxT, offT, stateA, (uint32_t*)U);
        gemm_kernel<<<dim3(8, 32), 256, 0, stream>>>(U, BtT, stateT);
    }
}

// Round 3
// 290.535 us; speedup vs baseline: 10.0027x; 1.3076x over previous
//
#include <hip/hip_runtime.h>
#include <hip/hip_bf16.h>
#include <stdint.h>

// Problem constants: NA=NT=1024, A_DIM=E_DIM=128, L=128, K = L*128 = 16384

typedef short bf16x8 __attribute__((ext_vector_type(8)));
typedef float f32x4  __attribute__((ext_vector_type(4)));

#define GLD16(g, l) __builtin_amdgcn_global_load_lds( \
    (const __attribute__((address_space(1))) void*)(uintptr_t)(g), \
    (__attribute__((address_space(3))) void*)(uintptr_t)(l), 16, 0, 0)

// ---------------- prep: transpose inputs [1024][1024] -> inputsT ----------------
__global__ __launch_bounds__(256) void transpose_int_kernel(const int* __restrict__ in,
                                                            int* __restrict__ out) {
    __shared__ int tile[32][33];
    int b = blockIdx.x;              // 1024 tiles
    int tr = b >> 5, tc = b & 31;
    int r0 = tr * 32, c0 = tc * 32;
    int tx = threadIdx.x & 31, ty = threadIdx.x >> 5;
#pragma unroll
    for (int p = 0; p < 4; ++p)
        tile[ty + p * 8][tx] = in[(size_t)(r0 + ty + p * 8) * 1024 + c0 + tx];
    __syncthreads();
#pragma unroll
    for (int p = 0; p < 4; ++p) {
        int cc = ty + p * 8;
        out[(size_t)(c0 + cc) * 1024 + r0 + tx] = tile[tx][cc];
    }
}

// ------------- prep: transpose+cast weights f32 [16384][128] -> bf16 [128][16384] -------------
__global__ __launch_bounds__(256) void transpose_w_kernel(const float* __restrict__ W0,
                                                          const float* __restrict__ W1,
                                                          uint16_t* __restrict__ O0,
                                                          uint16_t* __restrict__ O1) {
    __shared__ float tile[32][33];
    int b = blockIdx.x;              // 4096 tiles (2048 per weight)
    const float* W = W0;
    uint16_t* O = O0;
    if (b >= 2048) { b -= 2048; W = W1; O = O1; }
    int tr = b >> 2, tc = b & 3;
    int r0 = tr * 32, c0 = tc * 32;
    int tx = threadIdx.x & 31, ty = threadIdx.x >> 5;
#pragma unroll
    for (int p = 0; p < 4; ++p)
        tile[ty + p * 8][tx] = W[(size_t)(r0 + ty + p * 8) * 128 + c0 + tx];
    __syncthreads();
#pragma unroll
    for (int p = 0; p < 4; ++p) {
        int cc = ty + p * 8;
        __hip_bfloat16 h = __float2bfloat16(tile[tx][cc]);
        O[(size_t)(c0 + cc) * 16384 + r0 + tx] = *(uint16_t*)&h;
    }
}

// ---------------- prep: CSR build — parallel deterministic counting sort ----------------
// 128 threads; thread c owns chunk of 8 elements. Per-chunk hist (u16, own row, no
// atomics) + register local ranks + per-label column prefix (thread l owns column l).
// Produces indices sorted by (label, t) — identical ordering to a serial stable sort.
__global__ __launch_bounds__(128) void csr_build_kernel(const int* __restrict__ inA,
                                                        const int* __restrict__ inT,
                                                        uint16_t* __restrict__ idxA,
                                                        uint16_t* __restrict__ idxT,
                                                        int* __restrict__ offA,
                                                        int* __restrict__ offT) {
    __shared__ uint16_t chist[128][128];  // 32 KiB [chunk][label]
    __shared__ int lab[1024];             // 4 KiB
    __shared__ int tot[128];
    __shared__ int off[128];
    int b = blockIdx.x;
    const int* in = inA; uint16_t* idx = idxA; int* offo = offA; int row = b;
    if (b >= 1024) { in = inT; idx = idxT; offo = offT; row = b - 1024; }
    const int c = threadIdx.x;            // 0..127

    for (int i = c; i < 8192; i += 128) ((uint32_t*)chist)[i] = 0;
    for (int i = c; i < 1024; i += 128) lab[i] = in[(size_t)row * 1024 + i];
    __syncthreads();

    int mylab[8], rloc[8];
#pragma unroll
    for (int k = 0; k < 8; ++k) {
        int l = lab[c * 8 + k];
        mylab[k] = l;
        rloc[k] = chist[c][l];            // rank within own chunk
        chist[c][l] = (uint16_t)(rloc[k] + 1);
    }
    __syncthreads();

    // column prefix over chunks: thread c owns label l=c (2 lanes/bank -> free)
    {
        int run = 0;
#pragma unroll 4
        for (int ch = 0; ch < 128; ++ch) {
            int v = chist[ch][c];
            chist[ch][c] = (uint16_t)run;
            run += v;
        }
        tot[c] = run;
    }
    __syncthreads();
    if (c == 0) {
        int s = 0;
#pragma unroll 4
        for (int l = 0; l < 128; ++l) { off[l] = s; s += tot[l]; }
    }
    __syncthreads();
    offo[(size_t)row * 128 + c] = off[c];
#pragma unroll
    for (int k = 0; k < 8; ++k) {
        int l = mylab[k];
        int pos = off[l] + (int)chist[c][l] + rloc[k];
        idx[(size_t)row * 1024 + pos] = (uint16_t)(c * 8 + k);
    }
}

// ---------------- prep: init output (state lives in d_out, stride 256) ----------------
__global__ __launch_bounds__(256) void init_out_kernel(const float* __restrict__ fa,
                                                       const float* __restrict__ ft,
                                                       float* __restrict__ out) {
    int i = blockIdx.x * 256 + threadIdx.x;   // grid 2048 -> 524288
    int r = i >> 8, c = i & 255;
    float v = 0.f;
    if (c < 128) v = (r < 1024) ? fa[(size_t)r * 128 + c] : ft[(size_t)(r - 1024) * 128 + c];
    out[i] = v;
}

// ---------------- bucket via CSR: U[j, l*128+e] = sum_{t in list(j,l)} src[t][e] ----------------
// 1 block per j, 8 waves, 16 labels per wave, lane covers 2 e-channels.
// CSR row staged in LDS; gather loop unrolled x4 (4 loads in flight).
__global__ __launch_bounds__(512) void bucket_csr_kernel(const uint16_t* __restrict__ idx,
                                                         const int* __restrict__ off,
                                                         const float* __restrict__ src,   // stride 256
                                                         uint32_t* __restrict__ U32) {    // [1024][8192]
    __shared__ uint16_t sidx[1024];
    __shared__ int soff[129];
    const int j = blockIdx.x;
    const int tid = threadIdx.x;
    const int wv = tid >> 6, lane = tid & 63;

    if (tid < 512) {
        ((uint32_t*)sidx)[tid] = ((const uint32_t*)(idx + (size_t)j * 1024))[tid];
    }
    if (tid < 128) soff[tid] = off[(size_t)j * 128 + tid];
    if (tid == 0) soff[128] = 1024;
    __syncthreads();

#pragma unroll 1
    for (int li = 0; li < 16; ++li) {
        int l = wv * 16 + li;
        int s = soff[l];
        int e = soff[l + 1];
        float a0 = 0.f, a1 = 0.f, b0 = 0.f, b1 = 0.f;
        int p = s;
        for (; p + 3 < e; p += 4) {
            int t0 = sidx[p], t1 = sidx[p + 1], t2 = sidx[p + 2], t3 = sidx[p + 3];
            float2 v0 = *(const float2*)(src + (size_t)t0 * 256 + lane * 2);
            float2 v1 = *(const float2*)(src + (size_t)t1 * 256 + lane * 2);
            float2 v2 = *(const float2*)(src + (size_t)t2 * 256 + lane * 2);
            float2 v3 = *(const float2*)(src + (size_t)t3 * 256 + lane * 2);
            a0 += v0.x + v1.x; a1 += v0.y + v1.y;
            b0 += v2.x + v3.x; b1 += v2.y + v3.y;
        }
        for (; p < e; ++p) {
            int t0 = sidx[p];
            float2 v0 = *(const float2*)(src + (size_t)t0 * 256 + lane * 2);
            a0 += v0.x; a1 += v0.y;
        }
        float r0 = a0 + b0, r1 = a1 + b1;
        __hip_bfloat16 h0 = __float2bfloat16(r0), h1 = __float2bfloat16(r1);
        uint32_t pk = ((uint32_t)(*(uint16_t*)&h1) << 16) | (uint32_t)(*(uint16_t*)&h0);
        U32[(size_t)j * 8192 + l * 64 + lane] = pk;
    }
}

// ---------------- GEMM: state[1024][*256] += A[1024][16384] x Bt[128][16384]^T ----------------
// grid (8 m-tiles, 32 k-chunks), 256 threads = 4 waves (2x2), 64x64 per wave, 16x16x32 bf16 MFMA.
__global__ __launch_bounds__(256) void gemm_kernel(const uint16_t* __restrict__ A,
                                                   const uint16_t* __restrict__ Bt,
                                                   float* __restrict__ outacc) {
    __shared__ uint16_t Atile[128 * 64];   // 16 KiB, XOR-swizzled 16B slots
    __shared__ uint16_t Btile[128 * 64];

    const int tid = threadIdx.x;
    const int lane = tid & 63;
    const int wid = tid >> 6;
    const int wr = wid >> 1, wc = wid & 1;
    const int mbase = blockIdx.x * 128;
    const size_t kchunk = (size_t)blockIdx.y * 512;

    f32x4 acc[4][4] = {};

    const int rlane = lane >> 3;
    const int slane = lane & 7;

    for (int it = 0; it < 8; ++it) {
        const size_t kb2 = (kchunk + (size_t)it * 64) * 2;
#pragma unroll
        for (int c = 0; c < 4; ++c) {
            int r = c * 32 + wid * 8 + rlane;
            int col16 = slane ^ (r & 7);                     // pre-swizzled source (involution)
            const char* gA = (const char*)A + (size_t)(mbase + r) * 32768 + kb2 + col16 * 16;
            char* lA = (char*)Atile + c * 4096 + wid * 1024; // wave-uniform linear dest
            GLD16(gA, lA);
            const char* gB = (const char*)Bt + (size_t)r * 32768 + kb2 + col16 * 16;
            char* lB = (char*)Btile + c * 4096 + wid * 1024;
            GLD16(gB, lB);
        }
        __syncthreads();

#pragma unroll
        for (int kk = 0; kk < 2; ++kk) {
            bf16x8 af[4], bfr[4];
            const int q = lane >> 4;
            const int rl = lane & 15;
#pragma unroll
            for (int m = 0; m < 4; ++m) {
                int row = wr * 64 + m * 16 + rl;
                int sw = (kk * 4 + q) ^ (row & 7);
                af[m] = *(const bf16x8*)((const char*)Atile + row * 128 + sw * 16);
            }
#pragma unroll
            for (int n = 0; n < 4; ++n) {
                int row = wc * 64 + n * 16 + rl;
                int sw = (kk * 4 + q) ^ (row & 7);
                bfr[n] = *(const bf16x8*)((const char*)Btile + row * 128 + sw * 16);
            }
#pragma unroll
            for (int m = 0; m < 4; ++m)
#pragma unroll
                for (int n = 0; n < 4; ++n)
                    acc[m][n] = __builtin_amdgcn_mfma_f32_16x16x32_bf16(af[m], bfr[n], acc[m][n], 0, 0, 0);
        }
        __syncthreads();
    }

    const int rq = lane >> 4;   // C/D: col=lane&15, row=(lane>>4)*4+reg
    const int cn = lane & 15;
#pragma unroll
    for (int m = 0; m < 4; ++m)
#pragma unroll
        for (int n = 0; n < 4; ++n)
#pragma unroll
            for (int r = 0; r < 4; ++r) {
                int row = mbase + wr * 64 + m * 16 + rq * 4 + r;
                int col = wc * 64 + n * 16 + cn;
                unsafeAtomicAdd(&outacc[(size_t)row * 256 + col], acc[m][n][r]);
            }
}

extern "C" void kernel_launch(void* const* d_in, const int* in_sizes, int n_in,
                              void* d_out, int out_size, void* d_ws, size_t ws_size,
                              hipStream_t stream) {
    const int*   inputs  = (const int*)d_in[0];
    const float* first_a = (const float*)d_in[1];
    const float* first_t = (const float*)d_in[2];
    const float* Awij    = (const float*)d_in[3];
    const float* Awij2   = (const float*)d_in[4];
    float* out = (float*)d_out;

    // workspace layout (45 MiB total)
    char* w = (char*)d_ws;
    uint16_t* U       = (uint16_t*)(w);                 // 32 MiB  [1024][16384] bf16
    int*      inputsT = (int*)(w);                      // 4 MiB, prep-only, aliases U
    uint16_t* BtA     = (uint16_t*)(w + (32u << 20));   // 4 MiB  [a][l*128+e] = Awij2[l][e][a]
    uint16_t* BtT     = (uint16_t*)(w + (36u << 20));   // 4 MiB  [e][l*128+a] = Awij[l][a][e]
    uint16_t* idxA    = (uint16_t*)(w + (40u << 20));   // 2 MiB
    uint16_t* idxT    = (uint16_t*)(w + (42u << 20));   // 2 MiB
    int*      offA    = (int*)(w + (44u << 20));        // 512 KiB
    int*      offT    = (int*)(w + (44u << 20) + (1u << 19)); // 512 KiB
    if (ws_size < (45u << 20)) return;

    float* stateA = out;                 // [1024][256], cols 0..127 live
    float* stateT = out + 1024 * 256;    // [1024][256], cols 0..127 live

    transpose_int_kernel<<<1024, 256, 0, stream>>>(inputs, inputsT);
    transpose_w_kernel<<<4096, 256, 0, stream>>>(Awij2, Awij, BtA, BtT);
    csr_build_kernel<<<2048, 128, 0, stream>>>(inputs, inputsT, idxA, idxT, offA, offT);
    init_out_kernel<<<2048, 256, 0, stream>>>(first_a, first_t, out);

    for (int s = 0; s < 2; ++s) {
        // Phase A: a += bucket_t(update_t) x Awij2
        bucket_csr_kernel<<<1024, 512, 0, stream>>>(idxA, offA, stateT, (uint32_t*)U);
        gemm_kernel<<<dim3(8, 32), 256, 0, stream>>>(U, BtA, stateA);
        // Phase T: t += bucket_j(new_a) x Awij
        bucket_csr_kernel<<<1024, 512, 0, stream>>>(idxT, offT, stateA, (uint32_t*)U);
        gemm_kernel<<<dim3(8, 32), 256, 0, stream>>>(U, BtT, stateT);
    }
}